// Round 7
// baseline (412.122 us; speedup 1.0000x reference)
//
#include <hip/hip_runtime.h>
#include <hip/hip_fp16.h>

#define NEG_SLOPE 0.2f
#define BKN 128                 // nodes per bucket (pow2)
#define MAXNB 1024              // supports n <= 131072
#define GRP 256                 // pass1/ghist groups (blocks), private cursors

typedef _Float16 half_t;
typedef __attribute__((ext_vector_type(4))) _Float16 half4;
typedef __attribute__((ext_vector_type(8))) _Float16 half8;
typedef __attribute__((ext_vector_type(4))) float floatx4;

// ---------------------------------------------------------------------------
// Weight transpose + fp16 convert: Wt[n][k] = (fp16) W[k][n].  K=128 fixed.
// ---------------------------------------------------------------------------
__global__ __launch_bounds__(256) void w_convert(
    const float* __restrict__ W, half_t* __restrict__ Wt, int N)
{
    int i = blockIdx.x * 256 + threadIdx.x;      // i indexes W row-major (K*N)
    if (i >= 128 * N) return;
    int k = i / N, nn = i % N;
    Wt[nn * 128 + k] = (half_t)W[i];
}

// ---------------------------------------------------------------------------
// MFMA GEMM + fused attention logits (mfma 16x16x32 f16, fp32 acc).
// Block = 4 waves; M-tile 64. XOR chunk swizzle kills ds_read bank conflicts.
// ---------------------------------------------------------------------------
template<int BN, int HEADS>
__global__ __launch_bounds__(256) void gemm_mfma(
    const float* __restrict__ X, const half_t* __restrict__ Wt,
    const float* __restrict__ atts, const float* __restrict__ attd,
    half_t* __restrict__ H, float* __restrict__ As, float* __restrict__ Ad,
    int n)
{
    constexpr int K  = 128;
    constexpr int NT = BN / 16;           // col tiles
    constexpr int TPH = NT / HEADS;       // col tiles per head

    __shared__ half_t Wl[BN * K];
    __shared__ half_t Xl[64 * K];

    const int t = threadIdx.x;
    const int wave = t >> 6, lane = t & 63;
    const int quad = lane >> 4, c = lane & 15;

    float att_s[NT], att_d[NT];
    #pragma unroll
    for (int nt = 0; nt < NT; ++nt) {
        att_s[nt] = atts[nt * 16 + c];
        att_d[nt] = attd[nt * 16 + c];
    }

    for (int i = t; i < BN * 16; i += 256) {
        int row = i >> 4, cid = i & 15;
        half8 v = *(const half8*)(Wt + row * K + cid * 8);
        *(half8*)(Wl + row * K + ((cid ^ (row & 15)) << 3)) = v;
    }

    const int numTiles = (n + 63) / 64;
    for (int tile = blockIdx.x; tile < numTiles; tile += gridDim.x) {
        const int row0 = tile * 64;
        __syncthreads();
        for (int i = t; i < 1024; i += 256) {
            int m = i >> 4, cid = i & 15;
            int row = row0 + m;
            float4 a = make_float4(0.f,0.f,0.f,0.f), b = a;
            if (row < n) {
                const float4* src = (const float4*)(X + (size_t)row * K + cid * 8);
                a = src[0]; b = src[1];
            }
            half8 h;
            h[0]=(half_t)a.x; h[1]=(half_t)a.y; h[2]=(half_t)a.z; h[3]=(half_t)a.w;
            h[4]=(half_t)b.x; h[5]=(half_t)b.y; h[6]=(half_t)b.z; h[7]=(half_t)b.w;
            *(half8*)(Xl + m * K + ((cid ^ (m & 15)) << 3)) = h;
        }
        __syncthreads();

        floatx4 acc[NT];
        #pragma unroll
        for (int i = 0; i < NT; ++i) acc[i] = (floatx4)(0.f);

        #pragma unroll
        for (int kc = 0; kc < 4; ++kc) {
            int cid = kc * 4 + quad;
            half8 afrag = *(const half8*)(Xl + (wave * 16 + c) * K + ((cid ^ c) << 3));
            #pragma unroll
            for (int nt = 0; nt < NT; ++nt) {
                half8 bfrag = *(const half8*)(Wl + (nt * 16 + c) * K + ((cid ^ c) << 3));
                acc[nt] = __builtin_amdgcn_mfma_f32_16x16x32_f16(afrag, bfrag, acc[nt], 0, 0, 0);
            }
        }

        #pragma unroll
        for (int reg = 0; reg < 4; ++reg) {
            int row = row0 + wave * 16 + quad * 4 + reg;
            bool ok = row < n;
            if (ok) {
                #pragma unroll
                for (int nt = 0; nt < NT; ++nt)
                    H[(size_t)row * BN + nt * 16 + c] = (half_t)acc[nt][reg];
            }
            #pragma unroll
            for (int h = 0; h < HEADS; ++h) {
                float ps = 0.f, pd = 0.f;
                #pragma unroll
                for (int u = 0; u < TPH; ++u) {
                    int nt = h * TPH + u;
                    ps += acc[nt][reg] * att_s[nt];
                    pd += acc[nt][reg] * att_d[nt];
                }
                #pragma unroll
                for (int off = 1; off < 16; off <<= 1) {
                    ps += __shfl_xor(ps, off);
                    pd += __shfl_xor(pd, off);
                }
                if (ok && c == 0) {
                    As[(size_t)row * HEADS + h] = ps;
                    Ad[(size_t)row * HEADS + h] = pd;
                }
            }
        }
    }
}

// ---------------------------------------------------------------------------
// CSR build (contention-free bucketed counting sort, per-group cursors).
// pass2 additionally computes layer-1 edge weights (head-major fp16) and
// the bucket-local dst byte (for weights2).
// ---------------------------------------------------------------------------
__global__ __launch_bounds__(256) void ghist(
    const int* __restrict__ ei, int E, int Etot, int NB, int chunk,
    int* __restrict__ cnt)
{
    __shared__ int h[MAXNB];
    int g = blockIdx.x;
    for (int i = threadIdx.x; i < NB; i += 256) h[i] = 0;
    __syncthreads();
    int lo = g * chunk, hi = min(Etot, lo + chunk);
    for (int e = lo + threadIdx.x; e < hi; e += 256) {
        int dst = (e < E) ? ei[E + e] : (e - E);
        atomicAdd(&h[dst >> 7], 1);
    }
    __syncthreads();
    for (int i = threadIdx.x; i < NB; i += 256) cnt[i * GRP + g] = h[i];
}

__global__ __launch_bounds__(256) void scan_blocks(
    int* __restrict__ data, int n, int* __restrict__ bsum)
{
    __shared__ int s[256];
    int t = threadIdx.x;
    int idx = blockIdx.x * 1024 + t * 4;
    int4 v = make_int4(0, 0, 0, 0);
    if (idx + 3 < n)      v = *(const int4*)(data + idx);
    else {
        if (idx     < n) v.x = data[idx];
        if (idx + 1 < n) v.y = data[idx+1];
        if (idx + 2 < n) v.z = data[idx+2];
        if (idx + 3 < n) v.w = data[idx+3];
    }
    int tsum = v.x + v.y + v.z + v.w;
    s[t] = tsum;
    __syncthreads();
    for (int off = 1; off < 256; off <<= 1) {
        int x = (t >= off) ? s[t - off] : 0;
        __syncthreads();
        s[t] += x;
        __syncthreads();
    }
    int excl = s[t] - tsum;
    if (t == 255) bsum[blockIdx.x] = s[255];
    if (idx     < n) data[idx]     = excl;
    if (idx + 1 < n) data[idx + 1] = excl + v.x;
    if (idx + 2 < n) data[idx + 2] = excl + v.x + v.y;
    if (idx + 3 < n) data[idx + 3] = excl + v.x + v.y + v.z;
}

__global__ __launch_bounds__(256) void scan_sums(int* __restrict__ bsum, int nb)
{
    __shared__ int s[256];
    int t = threadIdx.x;
    int v = (t < nb) ? bsum[t] : 0;
    s[t] = v;
    __syncthreads();
    for (int off = 1; off < 256; off <<= 1) {
        int x = (t >= off) ? s[t - off] : 0;
        __syncthreads();
        s[t] += x;
        __syncthreads();
    }
    if (t < nb) bsum[t] = s[t] - v;
}

__global__ __launch_bounds__(256) void scan_add(
    int* __restrict__ data, int n, const int* __restrict__ bsum)
{
    int i = blockIdx.x * 256 + threadIdx.x;
    if (i < n) data[i] += bsum[i >> 10];
}

__global__ __launch_bounds__(256) void pass1_scatter(
    const int* __restrict__ ei, int E, int Etot, int NB, int chunk,
    const int* __restrict__ S, unsigned* __restrict__ tmp)
{
    __shared__ int cur[MAXNB];
    int g = blockIdx.x;
    for (int i = threadIdx.x; i < NB; i += 256) cur[i] = S[i * GRP + g];
    __syncthreads();
    int lo = g * chunk, hi = min(Etot, lo + chunk);
    for (int e = lo + threadIdx.x; e < hi; e += 256) {
        int src, dst;
        if (e < E) { src = ei[e]; dst = ei[E + e]; }
        else       { src = dst = e - E; }
        int pos = atomicAdd(&cur[dst >> 7], 1);   // LDS atomic, private row
        tmp[pos] = ((unsigned)src << 7) | (unsigned)(dst & (BKN - 1));
    }
}

// pass2: sort records within bucket; emit esrc, ldst, offs, and the four
// head-major layer-1 weight arrays w1[h*Etot + j] (fp16).
__global__ __launch_bounds__(256) void pass2_sort(
    const unsigned* __restrict__ tmp, const int* __restrict__ S,
    int NB, int Etot,
    const float* __restrict__ As1, const float* __restrict__ Ad1,
    int* __restrict__ offs, int* __restrict__ esrc,
    unsigned char* __restrict__ ldst, half_t* __restrict__ w1, int n)
{
    __shared__ int cnt[BKN];
    __shared__ int sc[BKN];
    __shared__ int cur[BKN];
    __shared__ float Adl[BKN * 4];
    int bk = blockIdx.x;
    int t  = threadIdx.x;
    if (t < BKN) cnt[t] = 0;
    // stage this bucket's Ad rows (128 nodes x 4 heads = 2KB)
    for (int i = t; i < BKN * 4; i += 256) {
        int idx = bk * BKN * 4 + i;
        Adl[i] = (idx < n * 4) ? Ad1[idx] : 0.f;
    }
    __syncthreads();
    int lo = S[bk * GRP];
    int hi = (bk + 1 < NB) ? S[(bk + 1) * GRP] : Etot;
    for (int i = lo + t; i < hi; i += 256)
        atomicAdd(&cnt[tmp[i] & (BKN - 1)], 1);
    __syncthreads();
    int v = (t < BKN) ? cnt[t] : 0;
    if (t < BKN) sc[t] = v;
    __syncthreads();
    for (int off = 1; off < BKN; off <<= 1) {
        int x = (t < BKN && t >= off) ? sc[t - off] : 0;
        __syncthreads();
        if (t < BKN) sc[t] += x;
        __syncthreads();
    }
    if (t < BKN) {
        int node = bk * BKN + t;
        if (node < n) offs[node] = lo + sc[t];   // inclusive scan -> end(v)
        cur[t] = lo + sc[t] - v;                 // exclusive -> begin cursor
    }
    __syncthreads();
    for (int i = lo + t; i < hi; i += 256) {
        unsigned w = tmp[i];
        int local = (int)(w & (BKN - 1));
        int src   = (int)(w >> 7);
        int p = atomicAdd(&cur[local], 1);
        esrc[p] = src;
        ldst[p] = (unsigned char)local;
        float4 a4 = *(const float4*)(As1 + 4 * src);
        #pragma unroll
        for (int h = 0; h < 4; ++h) {
            float e = ((const float*)&a4)[h] + Adl[local * 4 + h];
            e = e > 0.f ? e : NEG_SLOPE * e;
            w1[(size_t)h * Etot + p] = (half_t)__expf(e);
        }
    }
}

// layer-2 edge weights: one block per bucket; Ad2 for the bucket in LDS.
__global__ __launch_bounds__(256) void weights2(
    const int* __restrict__ esrc, const unsigned char* __restrict__ ldst,
    const int* __restrict__ offs,
    const float* __restrict__ As2, const float* __restrict__ Ad2,
    half_t* __restrict__ w2, int NB, int Etot, int n)
{
    __shared__ float Adl[BKN];
    int bk = blockIdx.x;
    int t  = threadIdx.x;
    if (t < BKN) {
        int node = bk * BKN + t;
        Adl[t] = (node < n) ? Ad2[node] : 0.f;
    }
    __syncthreads();
    int lo = bk ? offs[bk * BKN - 1] : 0;
    int last = min(bk * BKN + BKN - 1, n - 1);
    int hi = offs[last];
    for (int j = lo + t; j < hi; j += 256) {
        float e = As2[esrc[j]] + Adl[ldst[j]];
        e = e > 0.f ? e : NEG_SLOPE * e;
        w2[j] = (half_t)__expf(e);
    }
}

// ---------------------------------------------------------------------------
// Layer-1 aggregation: one wave per dst node, F=128 (fp16), 4 heads.
// Weights precomputed (head-major): wh = w1 + head*Etot, consumed as
// broadcast half4 per 4 edges. Fuses softmax-normalize + bias + ELU.
// ---------------------------------------------------------------------------
__global__ __launch_bounds__(256) void agg1(
    const int* __restrict__ offs, const int* __restrict__ esrc,
    const half_t* __restrict__ w1, const __half2* __restrict__ Hh,
    const float* __restrict__ bias, float* __restrict__ X2, int n, int Etot)
{
    int v    = (blockIdx.x * 256 + threadIdx.x) >> 6;
    int lane = threadIdx.x & 63;
    if (v >= n) return;
    int end = offs[v];
    int beg = v ? offs[v - 1] : 0;
    const half_t* wh = w1 + (size_t)(lane >> 4) * Etot;
    float accx = 0.f, accy = 0.f, den = 0.f;
    int j = beg;
    for (; j < end && (j & 3); ++j) {          // align to 4
        int s = esrc[j];
        float w = (float)wh[j];
        float2 f = __half22float2(Hh[(unsigned)s * 64 + lane]);
        accx += w * f.x; accy += w * f.y; den += w;
    }
    for (; j + 3 < end; j += 4) {
        int4 s = *(const int4*)(esrc + j);
        half4 wv = *(const half4*)(wh + j);
        __half2 q0 = Hh[(unsigned)s.x * 64 + lane];
        __half2 q1 = Hh[(unsigned)s.y * 64 + lane];
        __half2 q2 = Hh[(unsigned)s.z * 64 + lane];
        __half2 q3 = Hh[(unsigned)s.w * 64 + lane];
        float w0 = (float)wv[0], w1f = (float)wv[1];
        float w2f = (float)wv[2], w3 = (float)wv[3];
        float2 f0 = __half22float2(q0);
        float2 f1 = __half22float2(q1);
        float2 f2 = __half22float2(q2);
        float2 f3 = __half22float2(q3);
        accx += w0*f0.x + w1f*f1.x + w2f*f2.x + w3*f3.x;
        accy += w0*f0.y + w1f*f1.y + w2f*f2.y + w3*f3.y;
        den  += w0 + w1f + w2f + w3;
    }
    for (; j < end; ++j) {
        int s = esrc[j];
        float w = (float)wh[j];
        float2 f = __half22float2(Hh[(unsigned)s * 64 + lane]);
        accx += w * f.x; accy += w * f.y; den += w;
    }
    float inv = 1.f / (den + 1e-16f);
    float2 b = ((const float2*)bias)[lane];
    float ox = accx*inv + b.x, oy = accy*inv + b.y;
    ox = ox > 0.f ? ox : __expf(ox) - 1.f;     // ELU
    oy = oy > 0.f ? oy : __expf(oy) - 1.f;
    ((float2*)(X2 + (size_t)v * 128))[lane] = make_float2(ox, oy);
}

// ---------------------------------------------------------------------------
// Layer-2 aggregation: one wave per dst node, F=64 (fp16), 1 head.
// Half-wave h takes contiguous 4-edge sub-blocks of each aligned 8-block
// (vectorized esrc/w2 loads); scalar prologue/tail parity-split.
// ---------------------------------------------------------------------------
__global__ __launch_bounds__(256) void agg2(
    const int* __restrict__ offs, const int* __restrict__ esrc,
    const half_t* __restrict__ w2, const __half2* __restrict__ Hh,
    const float* __restrict__ bias, float* __restrict__ out, int n)
{
    int v    = (blockIdx.x * 256 + threadIdx.x) >> 6;
    int lane = threadIdx.x & 63;
    if (v >= n) return;
    int half = lane >> 5;
    int li   = lane & 31;
    int end = offs[v];
    int beg = v ? offs[v - 1] : 0;
    float accx = 0.f, accy = 0.f, den = 0.f;
    int alignEnd = min(end, (beg + 7) & ~7);
    for (int j = beg + half; j < alignEnd; j += 2) {   // prologue (parity)
        int s = esrc[j];
        float w = (float)w2[j];
        float2 f = __half22float2(Hh[(unsigned)s * 32 + li]);
        accx += w * f.x; accy += w * f.y; den += w;
    }
    int p = alignEnd;
    for (; p + 7 < end; p += 8) {
        int jb = p + half * 4;
        int4 s = *(const int4*)(esrc + jb);
        half4 wv = *(const half4*)(w2 + jb);
        __half2 q0 = Hh[(unsigned)s.x * 32 + li];
        __half2 q1 = Hh[(unsigned)s.y * 32 + li];
        __half2 q2 = Hh[(unsigned)s.z * 32 + li];
        __half2 q3 = Hh[(unsigned)s.w * 32 + li];
        float w0 = (float)wv[0], w1f = (float)wv[1];
        float w2f = (float)wv[2], w3 = (float)wv[3];
        float2 f0 = __half22float2(q0);
        float2 f1 = __half22float2(q1);
        float2 f2 = __half22float2(q2);
        float2 f3 = __half22float2(q3);
        accx += w0*f0.x + w1f*f1.x + w2f*f2.x + w3*f3.x;
        accy += w0*f0.y + w1f*f1.y + w2f*f2.y + w3*f3.y;
        den  += w0 + w1f + w2f + w3;
    }
    for (int j = p + half; j < end; j += 2) {          // tail (parity)
        int s = esrc[j];
        float w = (float)w2[j];
        float2 f = __half22float2(Hh[(unsigned)s * 32 + li]);
        accx += w * f.x; accy += w * f.y; den += w;
    }
    accx += __shfl_xor(accx, 32);
    accy += __shfl_xor(accy, 32);
    den  += __shfl_xor(den, 32);
    if (half == 0) {
        float inv = 1.f / (den + 1e-16f);
        float2 b = ((const float2*)bias)[li];
        ((float2*)(out + (size_t)v * 64))[li] =
            make_float2(accx*inv + b.x, accy*inv + b.y);
    }
}

extern "C" void kernel_launch(void* const* d_in, const int* in_sizes, int n_in,
                              void* d_out, int out_size, void* d_ws, size_t ws_size,
                              hipStream_t stream)
{
    (void)n_in; (void)out_size; (void)ws_size;
    const float* x   = (const float*)d_in[0];
    const int*   ei  = (const int*)  d_in[1];
    const float* W1  = (const float*)d_in[2];
    const float* as1 = (const float*)d_in[3];
    const float* ad1 = (const float*)d_in[4];
    const float* b1  = (const float*)d_in[5];
    const float* W2  = (const float*)d_in[6];
    const float* as2 = (const float*)d_in[7];
    const float* ad2 = (const float*)d_in[8];
    const float* b2  = (const float*)d_in[9];
    float* out = (float*)d_out;

    const int n    = in_sizes[0] / 128;   // 100000
    const int E    = in_sizes[1] / 2;     // 1600000
    const int Etot = E + n;               // + self loops
    const int NB   = (n + BKN - 1) / BKN; // buckets (782)
    const int chunk = (Etot + GRP - 1) / GRP;

    // Workspace layout (bytes). tmp overlays X2 (dead until agg1); w2
    // overlays w1 (dead after agg1).
    char* p = (char*)d_ws;
    half_t* Hh = (half_t*)p;  p += (size_t)n * 128 * sizeof(half_t);  // 25.6MB
    float* X2  = (float*)p;   p += (size_t)n * 128 * sizeof(float);   // 51.2MB
    float* As1 = (float*)p;   p += (size_t)n * 4 * sizeof(float);     // (L2: As2=n)
    float* Ad1 = (float*)p;   p += (size_t)n * 4 * sizeof(float);     // (L2: Ad2=n)
    int* offs  = (int*)p;     p += (size_t)n * sizeof(int);
    int* esrc  = (int*)p;     p += (size_t)Etot * sizeof(int);
    int* cnt   = (int*)p;     p += (size_t)NB * GRP * sizeof(int);    // 0.8MB
    int* bsum  = (int*)p;     p += 1024;
    half_t* Wt1 = (half_t*)p; p += 128 * 128 * sizeof(half_t);        // 32KB
    half_t* Wt2 = (half_t*)p; p += 64 * 128 * sizeof(half_t);         // 16KB
    half_t* w1 = (half_t*)p;  p += (size_t)4 * Etot * sizeof(half_t); // 13.6MB
    unsigned char* ldst = (unsigned char*)p;                          // Etot
    unsigned* tmp = (unsigned*)X2;        // overlay
    half_t* w2 = w1;                      // overlay

    const int scan_n  = NB * GRP;
    const int scan_nb = (scan_n + 1023) / 1024;   // <=256

    // ---- weight convert + layer-1 GEMM (independent of CSR) ----
    w_convert<<<(128 * 128 + 255) / 256, 256, 0, stream>>>(W1, Wt1, 128);
    w_convert<<<(128 * 64  + 255) / 256, 256, 0, stream>>>(W2, Wt2, 64);

    const int gtiles = (n + 63) / 64;
    gemm_mfma<128, 4><<<gtiles, 256, 0, stream>>>(x, Wt1, as1, ad1, Hh, As1, Ad1, n);

    // ---- CSR build (contention-free); pass2 also emits layer-1 weights ----
    ghist<<<GRP, 256, 0, stream>>>(ei, E, Etot, NB, chunk, cnt);
    scan_blocks<<<scan_nb, 256, 0, stream>>>(cnt, scan_n, bsum);
    scan_sums<<<1, 256, 0, stream>>>(bsum, scan_nb);
    scan_add<<<(scan_n + 255) / 256, 256, 0, stream>>>(cnt, scan_n, bsum);
    pass1_scatter<<<GRP, 256, 0, stream>>>(ei, E, Etot, NB, chunk, cnt, tmp);
    pass2_sort<<<NB, 256, 0, stream>>>(tmp, cnt, NB, Etot, As1, Ad1,
                                       offs, esrc, ldst, w1, n);

    // ---- Layer 1 aggregation (writes X2, consuming tmp's region) ----
    agg1<<<(n * 64 + 255) / 256, 256, 0, stream>>>(offs, esrc, w1,
        (const __half2*)Hh, b1, X2, n, Etot);

    // ---- Layer 2 ----
    gemm_mfma<64, 1><<<gtiles, 256, 0, stream>>>(X2, Wt2, as2, ad2, Hh, As1, Ad1, n);
    weights2<<<NB, 256, 0, stream>>>(esrc, ldst, offs, As1, Ad1, w2, NB, Etot, n);
    agg2<<<(n * 64 + 255) / 256, 256, 0, stream>>>(offs, esrc, w2,
        (const __half2*)Hh, b2, out, n);
}

// Round 8
// 381.031 us; speedup vs baseline: 1.0816x; 1.0816x over previous
//
#include <hip/hip_runtime.h>
#include <hip/hip_fp16.h>

#define NEG_SLOPE 0.2f
#define BKN 128                 // nodes per bucket (pow2)
#define MAXNB 1024              // supports n <= 131072
#define GRP 256                 // pass1/ghist groups (blocks), private cursors

typedef _Float16 half_t;
typedef __attribute__((ext_vector_type(8))) _Float16 half8;
typedef __attribute__((ext_vector_type(4))) float floatx4;

// ---------------------------------------------------------------------------
// Weight transpose + fp16 convert for BOTH layers in one launch.
//   Wt1[nn][k] = W1[k][nn]  (128x128), Wt2[nn][k] = W2[k][nn] (128x64)
// ---------------------------------------------------------------------------
__global__ __launch_bounds__(256) void w_convert2(
    const float* __restrict__ W1, half_t* __restrict__ Wt1,
    const float* __restrict__ W2, half_t* __restrict__ Wt2)
{
    int i = blockIdx.x * 256 + threadIdx.x;
    if (i < 128 * 128) {
        int k = i / 128, nn = i % 128;
        Wt1[nn * 128 + k] = (half_t)W1[i];
    } else if (i < 128 * 128 + 128 * 64) {
        int j = i - 128 * 128;
        int k = j / 64, nn = j % 64;
        Wt2[nn * 128 + k] = (half_t)W2[j];
    }
}

// ---------------------------------------------------------------------------
// MFMA GEMM + fused attention logits (mfma 16x16x32 f16, fp32 acc).
// Block = 4 waves; M-tile 64. XOR chunk swizzle kills ds_read bank conflicts.
// ---------------------------------------------------------------------------
template<int BN, int HEADS>
__global__ __launch_bounds__(256) void gemm_mfma(
    const float* __restrict__ X, const half_t* __restrict__ Wt,
    const float* __restrict__ atts, const float* __restrict__ attd,
    half_t* __restrict__ H, float* __restrict__ As, float* __restrict__ Ad,
    int n)
{
    constexpr int K  = 128;
    constexpr int NT = BN / 16;           // col tiles
    constexpr int TPH = NT / HEADS;       // col tiles per head

    __shared__ half_t Wl[BN * K];
    __shared__ half_t Xl[64 * K];

    const int t = threadIdx.x;
    const int wave = t >> 6, lane = t & 63;
    const int quad = lane >> 4, c = lane & 15;

    float att_s[NT], att_d[NT];
    #pragma unroll
    for (int nt = 0; nt < NT; ++nt) {
        att_s[nt] = atts[nt * 16 + c];
        att_d[nt] = attd[nt * 16 + c];
    }

    for (int i = t; i < BN * 16; i += 256) {
        int row = i >> 4, cid = i & 15;
        half8 v = *(const half8*)(Wt + row * K + cid * 8);
        *(half8*)(Wl + row * K + ((cid ^ (row & 15)) << 3)) = v;
    }

    const int numTiles = (n + 63) / 64;
    for (int tile = blockIdx.x; tile < numTiles; tile += gridDim.x) {
        const int row0 = tile * 64;
        __syncthreads();
        for (int i = t; i < 1024; i += 256) {
            int m = i >> 4, cid = i & 15;
            int row = row0 + m;
            float4 a = make_float4(0.f,0.f,0.f,0.f), b = a;
            if (row < n) {
                const float4* src = (const float4*)(X + (size_t)row * K + cid * 8);
                a = src[0]; b = src[1];
            }
            half8 h;
            h[0]=(half_t)a.x; h[1]=(half_t)a.y; h[2]=(half_t)a.z; h[3]=(half_t)a.w;
            h[4]=(half_t)b.x; h[5]=(half_t)b.y; h[6]=(half_t)b.z; h[7]=(half_t)b.w;
            *(half8*)(Xl + m * K + ((cid ^ (m & 15)) << 3)) = h;
        }
        __syncthreads();

        floatx4 acc[NT];
        #pragma unroll
        for (int i = 0; i < NT; ++i) acc[i] = (floatx4)(0.f);

        #pragma unroll
        for (int kc = 0; kc < 4; ++kc) {
            int cid = kc * 4 + quad;
            half8 afrag = *(const half8*)(Xl + (wave * 16 + c) * K + ((cid ^ c) << 3));
            #pragma unroll
            for (int nt = 0; nt < NT; ++nt) {
                half8 bfrag = *(const half8*)(Wl + (nt * 16 + c) * K + ((cid ^ c) << 3));
                acc[nt] = __builtin_amdgcn_mfma_f32_16x16x32_f16(afrag, bfrag, acc[nt], 0, 0, 0);
            }
        }

        #pragma unroll
        for (int reg = 0; reg < 4; ++reg) {
            int row = row0 + wave * 16 + quad * 4 + reg;
            bool ok = row < n;
            if (ok) {
                #pragma unroll
                for (int nt = 0; nt < NT; ++nt)
                    H[(size_t)row * BN + nt * 16 + c] = (half_t)acc[nt][reg];
            }
            #pragma unroll
            for (int h = 0; h < HEADS; ++h) {
                float ps = 0.f, pd = 0.f;
                #pragma unroll
                for (int u = 0; u < TPH; ++u) {
                    int nt = h * TPH + u;
                    ps += acc[nt][reg] * att_s[nt];
                    pd += acc[nt][reg] * att_d[nt];
                }
                #pragma unroll
                for (int off = 1; off < 16; off <<= 1) {
                    ps += __shfl_xor(ps, off);
                    pd += __shfl_xor(pd, off);
                }
                if (ok && c == 0) {
                    As[(size_t)row * HEADS + h] = ps;
                    Ad[(size_t)row * HEADS + h] = pd;
                }
            }
        }
    }
}

// ---------------------------------------------------------------------------
// CSR build (contention-free bucketed counting sort, per-group cursors).
// ---------------------------------------------------------------------------
__global__ __launch_bounds__(256) void ghist(
    const int* __restrict__ ei, int E, int Etot, int NB, int chunk,
    int* __restrict__ cnt)
{
    __shared__ int h[MAXNB];
    int g = blockIdx.x;
    for (int i = threadIdx.x; i < NB; i += 256) h[i] = 0;
    __syncthreads();
    int lo = g * chunk, hi = min(Etot, lo + chunk);
    for (int e = lo + threadIdx.x; e < hi; e += 256) {
        int dst = (e < E) ? ei[E + e] : (e - E);
        atomicAdd(&h[dst >> 7], 1);
    }
    __syncthreads();
    for (int i = threadIdx.x; i < NB; i += 256) cnt[i * GRP + g] = h[i];
}

__global__ __launch_bounds__(256) void scan_blocks(
    int* __restrict__ data, int n, int* __restrict__ bsum)
{
    __shared__ int s[256];
    int t = threadIdx.x;
    int idx = blockIdx.x * 1024 + t * 4;
    int4 v = make_int4(0, 0, 0, 0);
    if (idx + 3 < n)      v = *(const int4*)(data + idx);
    else {
        if (idx     < n) v.x = data[idx];
        if (idx + 1 < n) v.y = data[idx+1];
        if (idx + 2 < n) v.z = data[idx+2];
        if (idx + 3 < n) v.w = data[idx+3];
    }
    int tsum = v.x + v.y + v.z + v.w;
    s[t] = tsum;
    __syncthreads();
    for (int off = 1; off < 256; off <<= 1) {
        int x = (t >= off) ? s[t - off] : 0;
        __syncthreads();
        s[t] += x;
        __syncthreads();
    }
    int excl = s[t] - tsum;
    if (t == 255) bsum[blockIdx.x] = s[255];
    if (idx     < n) data[idx]     = excl;
    if (idx + 1 < n) data[idx + 1] = excl + v.x;
    if (idx + 2 < n) data[idx + 2] = excl + v.x + v.y;
    if (idx + 3 < n) data[idx + 3] = excl + v.x + v.y + v.z;
}

__global__ __launch_bounds__(256) void scan_sums(int* __restrict__ bsum, int nb)
{
    __shared__ int s[256];
    int t = threadIdx.x;
    int v = (t < nb) ? bsum[t] : 0;
    s[t] = v;
    __syncthreads();
    for (int off = 1; off < 256; off <<= 1) {
        int x = (t >= off) ? s[t - off] : 0;
        __syncthreads();
        s[t] += x;
        __syncthreads();
    }
    if (t < nb) bsum[t] = s[t] - v;
}

__global__ __launch_bounds__(256) void scan_add(
    int* __restrict__ data, int n, const int* __restrict__ bsum)
{
    int i = blockIdx.x * 256 + threadIdx.x;
    if (i < n) data[i] += bsum[i >> 10];
}

__global__ __launch_bounds__(256) void pass1_scatter(
    const int* __restrict__ ei, int E, int Etot, int NB, int chunk,
    const int* __restrict__ S, unsigned* __restrict__ tmp)
{
    __shared__ int cur[MAXNB];
    int g = blockIdx.x;
    for (int i = threadIdx.x; i < NB; i += 256) cur[i] = S[i * GRP + g];
    __syncthreads();
    int lo = g * chunk, hi = min(Etot, lo + chunk);
    for (int e = lo + threadIdx.x; e < hi; e += 256) {
        int src, dst;
        if (e < E) { src = ei[e]; dst = ei[E + e]; }
        else       { src = dst = e - E; }
        int pos = atomicAdd(&cur[dst >> 7], 1);   // LDS atomic, private row
        tmp[pos] = ((unsigned)src << 7) | (unsigned)(dst & (BKN - 1));
    }
}

__global__ __launch_bounds__(256) void pass2_sort(
    const unsigned* __restrict__ tmp, const int* __restrict__ S,
    int NB, int Etot,
    int* __restrict__ offs, int* __restrict__ esrc, int n)
{
    __shared__ int cnt[BKN];
    __shared__ int sc[BKN];
    __shared__ int cur[BKN];
    int bk = blockIdx.x;
    int t  = threadIdx.x;
    if (t < BKN) cnt[t] = 0;
    __syncthreads();
    int lo = S[bk * GRP];
    int hi = (bk + 1 < NB) ? S[(bk + 1) * GRP] : Etot;
    for (int i = lo + t; i < hi; i += 256)
        atomicAdd(&cnt[tmp[i] & (BKN - 1)], 1);
    __syncthreads();
    int v = (t < BKN) ? cnt[t] : 0;
    if (t < BKN) sc[t] = v;
    __syncthreads();
    for (int off = 1; off < BKN; off <<= 1) {
        int x = (t < BKN && t >= off) ? sc[t - off] : 0;
        __syncthreads();
        if (t < BKN) sc[t] += x;
        __syncthreads();
    }
    if (t < BKN) {
        int node = bk * BKN + t;
        if (node < n) offs[node] = lo + sc[t];   // inclusive scan -> end(v)
        cur[t] = lo + sc[t] - v;                 // exclusive -> begin cursor
    }
    __syncthreads();
    for (int i = lo + t; i < hi; i += 256) {
        unsigned w = tmp[i];
        int p = atomicAdd(&cur[w & (BKN - 1)], 1);
        esrc[p] = (int)(w >> 7);
    }
}

// ---------------------------------------------------------------------------
// Layer-1 aggregation: one wave per dst node, F=128 (fp16), 4 heads (C=32).
// Lane l -> feature pair (2l,2l+1), head l>>4. Edge loop unrolled x8 so 8
// independent H-row gathers (+8 As gathers) are in flight per wave.
// Fuses softmax normalization + bias + ELU; writes fp32 X2 directly.
// ---------------------------------------------------------------------------
__global__ __launch_bounds__(256) void agg1(
    const int* __restrict__ offs, const int* __restrict__ esrc,
    const __half2* __restrict__ Hh, const float* __restrict__ As,
    const float* __restrict__ Ad, const float* __restrict__ bias,
    float* __restrict__ X2, int n)
{
    int v    = (blockIdx.x * 256 + threadIdx.x) >> 6;
    int lane = threadIdx.x & 63;
    if (v >= n) return;
    int end = offs[v];
    int beg = v ? offs[v - 1] : 0;
    int head = lane >> 4;
    float adv = Ad[(size_t)v * 4 + head];
    float accx = 0.f, accy = 0.f, den = 0.f;
    int j = beg;
    for (; j < end && (j & 3); ++j) {       // align to 4 for int4 loads
        int s = esrc[j];
        float e = As[(size_t)s*4 + head] + adv;
        e = e > 0.f ? e : NEG_SLOPE*e;
        float w = __expf(e);
        float2 f = __half22float2(Hh[(unsigned)s * 64 + lane]);
        accx += w*f.x; accy += w*f.y; den += w;
    }
    for (; j + 7 < end; j += 8) {
        int4 sa = *(const int4*)(esrc + j);
        int4 sb = *(const int4*)(esrc + j + 4);
        float e0 = As[(size_t)sa.x*4 + head] + adv;
        float e1 = As[(size_t)sa.y*4 + head] + adv;
        float e2 = As[(size_t)sa.z*4 + head] + adv;
        float e3 = As[(size_t)sa.w*4 + head] + adv;
        float e4 = As[(size_t)sb.x*4 + head] + adv;
        float e5 = As[(size_t)sb.y*4 + head] + adv;
        float e6 = As[(size_t)sb.z*4 + head] + adv;
        float e7 = As[(size_t)sb.w*4 + head] + adv;
        __half2 q0 = Hh[(unsigned)sa.x * 64 + lane];
        __half2 q1 = Hh[(unsigned)sa.y * 64 + lane];
        __half2 q2 = Hh[(unsigned)sa.z * 64 + lane];
        __half2 q3 = Hh[(unsigned)sa.w * 64 + lane];
        __half2 q4 = Hh[(unsigned)sb.x * 64 + lane];
        __half2 q5 = Hh[(unsigned)sb.y * 64 + lane];
        __half2 q6 = Hh[(unsigned)sb.z * 64 + lane];
        __half2 q7 = Hh[(unsigned)sb.w * 64 + lane];
        e0 = e0 > 0.f ? e0 : NEG_SLOPE*e0;  float w0 = __expf(e0);
        e1 = e1 > 0.f ? e1 : NEG_SLOPE*e1;  float w1 = __expf(e1);
        e2 = e2 > 0.f ? e2 : NEG_SLOPE*e2;  float w2 = __expf(e2);
        e3 = e3 > 0.f ? e3 : NEG_SLOPE*e3;  float w3 = __expf(e3);
        e4 = e4 > 0.f ? e4 : NEG_SLOPE*e4;  float w4 = __expf(e4);
        e5 = e5 > 0.f ? e5 : NEG_SLOPE*e5;  float w5 = __expf(e5);
        e6 = e6 > 0.f ? e6 : NEG_SLOPE*e6;  float w6 = __expf(e6);
        e7 = e7 > 0.f ? e7 : NEG_SLOPE*e7;  float w7 = __expf(e7);
        float2 f0 = __half22float2(q0);
        float2 f1 = __half22float2(q1);
        float2 f2 = __half22float2(q2);
        float2 f3 = __half22float2(q3);
        float2 f4 = __half22float2(q4);
        float2 f5 = __half22float2(q5);
        float2 f6 = __half22float2(q6);
        float2 f7 = __half22float2(q7);
        accx += w0*f0.x + w1*f1.x + w2*f2.x + w3*f3.x
              + w4*f4.x + w5*f5.x + w6*f6.x + w7*f7.x;
        accy += w0*f0.y + w1*f1.y + w2*f2.y + w3*f3.y
              + w4*f4.y + w5*f5.y + w6*f6.y + w7*f7.y;
        den  += w0 + w1 + w2 + w3 + w4 + w5 + w6 + w7;
    }
    for (; j < end; ++j) {
        int s = esrc[j];
        float e = As[(size_t)s*4 + head] + adv;
        e = e > 0.f ? e : NEG_SLOPE*e;
        float w = __expf(e);
        float2 f = __half22float2(Hh[(unsigned)s * 64 + lane]);
        accx += w*f.x; accy += w*f.y; den += w;
    }
    float inv = 1.f / (den + 1e-16f);
    float2 b = ((const float2*)bias)[lane];
    float ox = accx*inv + b.x, oy = accy*inv + b.y;
    ox = ox > 0.f ? ox : __expf(ox) - 1.f;     // ELU
    oy = oy > 0.f ? oy : __expf(oy) - 1.f;
    ((float2*)(X2 + (size_t)v * 128))[lane] = make_float2(ox, oy);
}

// ---------------------------------------------------------------------------
// Layer-2 aggregation: one wave per dst node, F=64 (fp16), 1 head.
// Aligned 16-edge blocks: half-wave h takes 8 contiguous edges (2x int4),
// giving 8 H-row gathers in flight per half; parity prologue/tail.
// ---------------------------------------------------------------------------
__global__ __launch_bounds__(256) void agg2(
    const int* __restrict__ offs, const int* __restrict__ esrc,
    const __half2* __restrict__ Hh, const float* __restrict__ As,
    const float* __restrict__ Ad, const float* __restrict__ bias,
    float* __restrict__ out, int n)
{
    int v    = (blockIdx.x * 256 + threadIdx.x) >> 6;
    int lane = threadIdx.x & 63;
    if (v >= n) return;
    int half = lane >> 5;
    int li   = lane & 31;
    int end = offs[v];
    int beg = v ? offs[v - 1] : 0;
    float adv = Ad[v];
    float accx = 0.f, accy = 0.f, den = 0.f;
    int alignEnd = min(end, (beg + 15) & ~15);
    for (int j = beg + half; j < alignEnd; j += 2) {   // prologue (parity)
        int s = esrc[j];
        float e = As[s] + adv;
        e = e > 0.f ? e : NEG_SLOPE*e;
        float w = __expf(e);
        float2 f = __half22float2(Hh[(unsigned)s * 32 + li]);
        accx += w * f.x; accy += w * f.y; den += w;
    }
    int p = alignEnd;
    for (; p + 15 < end; p += 16) {
        int jb = p + half * 8;
        int4 sa = *(const int4*)(esrc + jb);
        int4 sb = *(const int4*)(esrc + jb + 4);
        float e0 = As[sa.x] + adv;
        float e1 = As[sa.y] + adv;
        float e2 = As[sa.z] + adv;
        float e3 = As[sa.w] + adv;
        float e4 = As[sb.x] + adv;
        float e5 = As[sb.y] + adv;
        float e6 = As[sb.z] + adv;
        float e7 = As[sb.w] + adv;
        __half2 q0 = Hh[(unsigned)sa.x * 32 + li];
        __half2 q1 = Hh[(unsigned)sa.y * 32 + li];
        __half2 q2 = Hh[(unsigned)sa.z * 32 + li];
        __half2 q3 = Hh[(unsigned)sa.w * 32 + li];
        __half2 q4 = Hh[(unsigned)sb.x * 32 + li];
        __half2 q5 = Hh[(unsigned)sb.y * 32 + li];
        __half2 q6 = Hh[(unsigned)sb.z * 32 + li];
        __half2 q7 = Hh[(unsigned)sb.w * 32 + li];
        e0 = e0 > 0.f ? e0 : NEG_SLOPE*e0;  float w0 = __expf(e0);
        e1 = e1 > 0.f ? e1 : NEG_SLOPE*e1;  float w1 = __expf(e1);
        e2 = e2 > 0.f ? e2 : NEG_SLOPE*e2;  float w2 = __expf(e2);
        e3 = e3 > 0.f ? e3 : NEG_SLOPE*e3;  float w3 = __expf(e3);
        e4 = e4 > 0.f ? e4 : NEG_SLOPE*e4;  float w4 = __expf(e4);
        e5 = e5 > 0.f ? e5 : NEG_SLOPE*e5;  float w5 = __expf(e5);
        e6 = e6 > 0.f ? e6 : NEG_SLOPE*e6;  float w6 = __expf(e6);
        e7 = e7 > 0.f ? e7 : NEG_SLOPE*e7;  float w7 = __expf(e7);
        float2 f0 = __half22float2(q0);
        float2 f1 = __half22float2(q1);
        float2 f2 = __half22float2(q2);
        float2 f3 = __half22float2(q3);
        float2 f4 = __half22float2(q4);
        float2 f5 = __half22float2(q5);
        float2 f6 = __half22float2(q6);
        float2 f7 = __half22float2(q7);
        accx += w0*f0.x + w1*f1.x + w2*f2.x + w3*f3.x
              + w4*f4.x + w5*f5.x + w6*f6.x + w7*f7.x;
        accy += w0*f0.y + w1*f1.y + w2*f2.y + w3*f3.y
              + w4*f4.y + w5*f5.y + w6*f6.y + w7*f7.y;
        den  += w0 + w1 + w2 + w3 + w4 + w5 + w6 + w7;
    }
    for (int j = p + half; j < end; j += 2) {          // tail (parity)
        int s = esrc[j];
        float e = As[s] + adv;
        e = e > 0.f ? e : NEG_SLOPE*e;
        float w = __expf(e);
        float2 f = __half22float2(Hh[(unsigned)s * 32 + li]);
        accx += w * f.x; accy += w * f.y; den += w;
    }
    accx += __shfl_xor(accx, 32);
    accy += __shfl_xor(accy, 32);
    den  += __shfl_xor(den, 32);
    if (half == 0) {
        float inv = 1.f / (den + 1e-16f);
        float2 b = ((const float2*)bias)[li];
        ((float2*)(out + (size_t)v * 64))[li] =
            make_float2(accx*inv + b.x, accy*inv + b.y);
    }
}

extern "C" void kernel_launch(void* const* d_in, const int* in_sizes, int n_in,
                              void* d_out, int out_size, void* d_ws, size_t ws_size,
                              hipStream_t stream)
{
    (void)n_in; (void)out_size; (void)ws_size;
    const float* x   = (const float*)d_in[0];
    const int*   ei  = (const int*)  d_in[1];
    const float* W1  = (const float*)d_in[2];
    const float* as1 = (const float*)d_in[3];
    const float* ad1 = (const float*)d_in[4];
    const float* b1  = (const float*)d_in[5];
    const float* W2  = (const float*)d_in[6];
    const float* as2 = (const float*)d_in[7];
    const float* ad2 = (const float*)d_in[8];
    const float* b2  = (const float*)d_in[9];
    float* out = (float*)d_out;

    const int n    = in_sizes[0] / 128;   // 100000
    const int E    = in_sizes[1] / 2;     // 1600000
    const int Etot = E + n;               // + self loops
    const int NB   = (n + BKN - 1) / BKN; // buckets (782)
    const int chunk = (Etot + GRP - 1) / GRP;

    // Workspace layout (bytes). Layer-2 buffers overlay consumed layer-1 ones.
    char* p = (char*)d_ws;
    half_t* Hh = (half_t*)p;  p += (size_t)n * 128 * sizeof(half_t);  // 25.6MB
    float* X2  = (float*)p;   p += (size_t)n * 128 * sizeof(float);   // 51.2MB
    float* As1 = (float*)p;   p += (size_t)n * 4 * sizeof(float);     // (L2: As2=n)
    float* Ad1 = (float*)p;   p += (size_t)n * 4 * sizeof(float);     // (L2: Ad2=n)
    int* offs  = (int*)p;     p += (size_t)n * sizeof(int);
    int* esrc  = (int*)p;     p += (size_t)Etot * sizeof(int);
    unsigned* tmp = (unsigned*)p; p += (size_t)Etot * sizeof(unsigned);
    int* cnt   = (int*)p;     p += (size_t)NB * GRP * sizeof(int);    // 0.8MB
    int* bsum  = (int*)p;     p += 1024;
    half_t* Wt1 = (half_t*)p; p += 128 * 128 * sizeof(half_t);        // 32KB
    half_t* Wt2 = (half_t*)p; p += 64 * 128 * sizeof(half_t);         // 16KB

    const int scan_n  = NB * GRP;
    const int scan_nb = (scan_n + 1023) / 1024;   // <=256

    // ---- weight convert (both layers, one launch) ----
    w_convert2<<<(128 * 192 + 255) / 256, 256, 0, stream>>>(W1, Wt1, W2, Wt2);

    // ---- CSR build (contention-free bucketed counting sort) ----
    ghist<<<GRP, 256, 0, stream>>>(ei, E, Etot, NB, chunk, cnt);
    scan_blocks<<<scan_nb, 256, 0, stream>>>(cnt, scan_n, bsum);
    scan_sums<<<1, 256, 0, stream>>>(bsum, scan_nb);
    scan_add<<<(scan_n + 255) / 256, 256, 0, stream>>>(cnt, scan_n, bsum);
    pass1_scatter<<<GRP, 256, 0, stream>>>(ei, E, Etot, NB, chunk, cnt, tmp);
    pass2_sort<<<NB, 256, 0, stream>>>(tmp, cnt, NB, Etot, offs, esrc, n);

    const int gtiles = (n + 63) / 64;

    // ---- Layer 1 ----
    gemm_mfma<128, 4><<<gtiles, 256, 0, stream>>>(x, Wt1, as1, ad1, Hh, As1, Ad1, n);
    agg1<<<(n * 64 + 255) / 256, 256, 0, stream>>>(offs, esrc, (const __half2*)Hh, As1, Ad1, b1, X2, n);

    // ---- Layer 2 ----
    gemm_mfma<64, 1><<<gtiles, 256, 0, stream>>>(X2, Wt2, as2, ad2, Hh, As1, Ad1, n);
    agg2<<<(n * 64 + 255) / 256, 256, 0, stream>>>(offs, esrc, (const __half2*)Hh, As1, Ad1, b2, out, n);
}

// Round 9
// 338.618 us; speedup vs baseline: 1.2171x; 1.1253x over previous
//
#include <hip/hip_runtime.h>
#include <hip/hip_fp16.h>

#define NEG_SLOPE 0.2f
#define BKN 128                 // nodes per bucket (pow2)
#define MAXNB 1024              // supports n <= 131072
#define GRP 256                 // pass1/ghist groups (blocks), private cursors

typedef _Float16 half_t;
typedef __attribute__((ext_vector_type(4))) _Float16 half4;
typedef __attribute__((ext_vector_type(8))) _Float16 half8;
typedef __attribute__((ext_vector_type(4))) float floatx4;

__device__ __forceinline__ float4 h4_to_f4(half4 h) {
    return make_float4((float)h[0], (float)h[1], (float)h[2], (float)h[3]);
}

// ---------------------------------------------------------------------------
// Weight transpose + fp16 convert for BOTH layers in one launch.
// ---------------------------------------------------------------------------
__global__ __launch_bounds__(256) void w_convert2(
    const float* __restrict__ W1, half_t* __restrict__ Wt1,
    const float* __restrict__ W2, half_t* __restrict__ Wt2)
{
    int i = blockIdx.x * 256 + threadIdx.x;
    if (i < 128 * 128) {
        int k = i / 128, nn = i % 128;
        Wt1[nn * 128 + k] = (half_t)W1[i];
    } else if (i < 128 * 128 + 128 * 64) {
        int j = i - 128 * 128;
        int k = j / 64, nn = j % 64;
        Wt2[nn * 128 + k] = (half_t)W2[j];
    }
}

// ---------------------------------------------------------------------------
// MFMA GEMM + fused attention logits (mfma 16x16x32 f16, fp32 acc).
// Block = 4 waves; M-tile 64. XOR chunk swizzle kills ds_read bank conflicts.
// ---------------------------------------------------------------------------
template<int BN, int HEADS>
__global__ __launch_bounds__(256) void gemm_mfma(
    const float* __restrict__ X, const half_t* __restrict__ Wt,
    const float* __restrict__ atts, const float* __restrict__ attd,
    half_t* __restrict__ H, float* __restrict__ As, float* __restrict__ Ad,
    int n)
{
    constexpr int K  = 128;
    constexpr int NT = BN / 16;           // col tiles
    constexpr int TPH = NT / HEADS;       // col tiles per head

    __shared__ half_t Wl[BN * K];
    __shared__ half_t Xl[64 * K];

    const int t = threadIdx.x;
    const int wave = t >> 6, lane = t & 63;
    const int quad = lane >> 4, c = lane & 15;

    float att_s[NT], att_d[NT];
    #pragma unroll
    for (int nt = 0; nt < NT; ++nt) {
        att_s[nt] = atts[nt * 16 + c];
        att_d[nt] = attd[nt * 16 + c];
    }

    for (int i = t; i < BN * 16; i += 256) {
        int row = i >> 4, cid = i & 15;
        half8 v = *(const half8*)(Wt + row * K + cid * 8);
        *(half8*)(Wl + row * K + ((cid ^ (row & 15)) << 3)) = v;
    }

    const int numTiles = (n + 63) / 64;
    for (int tile = blockIdx.x; tile < numTiles; tile += gridDim.x) {
        const int row0 = tile * 64;
        __syncthreads();
        for (int i = t; i < 1024; i += 256) {
            int m = i >> 4, cid = i & 15;
            int row = row0 + m;
            float4 a = make_float4(0.f,0.f,0.f,0.f), b = a;
            if (row < n) {
                const float4* src = (const float4*)(X + (size_t)row * K + cid * 8);
                a = src[0]; b = src[1];
            }
            half8 h;
            h[0]=(half_t)a.x; h[1]=(half_t)a.y; h[2]=(half_t)a.z; h[3]=(half_t)a.w;
            h[4]=(half_t)b.x; h[5]=(half_t)b.y; h[6]=(half_t)b.z; h[7]=(half_t)b.w;
            *(half8*)(Xl + m * K + ((cid ^ (m & 15)) << 3)) = h;
        }
        __syncthreads();

        floatx4 acc[NT];
        #pragma unroll
        for (int i = 0; i < NT; ++i) acc[i] = (floatx4)(0.f);

        #pragma unroll
        for (int kc = 0; kc < 4; ++kc) {
            int cid = kc * 4 + quad;
            half8 afrag = *(const half8*)(Xl + (wave * 16 + c) * K + ((cid ^ c) << 3));
            #pragma unroll
            for (int nt = 0; nt < NT; ++nt) {
                half8 bfrag = *(const half8*)(Wl + (nt * 16 + c) * K + ((cid ^ c) << 3));
                acc[nt] = __builtin_amdgcn_mfma_f32_16x16x32_f16(afrag, bfrag, acc[nt], 0, 0, 0);
            }
        }

        #pragma unroll
        for (int reg = 0; reg < 4; ++reg) {
            int row = row0 + wave * 16 + quad * 4 + reg;
            bool ok = row < n;
            if (ok) {
                #pragma unroll
                for (int nt = 0; nt < NT; ++nt)
                    H[(size_t)row * BN + nt * 16 + c] = (half_t)acc[nt][reg];
            }
            #pragma unroll
            for (int h = 0; h < HEADS; ++h) {
                float ps = 0.f, pd = 0.f;
                #pragma unroll
                for (int u = 0; u < TPH; ++u) {
                    int nt = h * TPH + u;
                    ps += acc[nt][reg] * att_s[nt];
                    pd += acc[nt][reg] * att_d[nt];
                }
                #pragma unroll
                for (int off = 1; off < 16; off <<= 1) {
                    ps += __shfl_xor(ps, off);
                    pd += __shfl_xor(pd, off);
                }
                if (ok && c == 0) {
                    As[(size_t)row * HEADS + h] = ps;
                    Ad[(size_t)row * HEADS + h] = pd;
                }
            }
        }
    }
}

// ---------------------------------------------------------------------------
// CSR build (contention-free bucketed counting sort, per-group cursors).
// ---------------------------------------------------------------------------
__global__ __launch_bounds__(256) void ghist(
    const int* __restrict__ ei, int E, int Etot, int NB, int chunk,
    int* __restrict__ cnt)
{
    __shared__ int h[MAXNB];
    int g = blockIdx.x;
    for (int i = threadIdx.x; i < NB; i += 256) h[i] = 0;
    __syncthreads();
    int lo = g * chunk, hi = min(Etot, lo + chunk);
    for (int e = lo + threadIdx.x; e < hi; e += 256) {
        int dst = (e < E) ? ei[E + e] : (e - E);
        atomicAdd(&h[dst >> 7], 1);
    }
    __syncthreads();
    for (int i = threadIdx.x; i < NB; i += 256) cnt[i * GRP + g] = h[i];
}

__global__ __launch_bounds__(256) void scan_blocks(
    int* __restrict__ data, int n, int* __restrict__ bsum)
{
    __shared__ int s[256];
    int t = threadIdx.x;
    int idx = blockIdx.x * 1024 + t * 4;
    int4 v = make_int4(0, 0, 0, 0);
    if (idx + 3 < n)      v = *(const int4*)(data + idx);
    else {
        if (idx     < n) v.x = data[idx];
        if (idx + 1 < n) v.y = data[idx+1];
        if (idx + 2 < n) v.z = data[idx+2];
        if (idx + 3 < n) v.w = data[idx+3];
    }
    int tsum = v.x + v.y + v.z + v.w;
    s[t] = tsum;
    __syncthreads();
    for (int off = 1; off < 256; off <<= 1) {
        int x = (t >= off) ? s[t - off] : 0;
        __syncthreads();
        s[t] += x;
        __syncthreads();
    }
    int excl = s[t] - tsum;
    if (t == 255) bsum[blockIdx.x] = s[255];
    if (idx     < n) data[idx]     = excl;
    if (idx + 1 < n) data[idx + 1] = excl + v.x;
    if (idx + 2 < n) data[idx + 2] = excl + v.x + v.y;
    if (idx + 3 < n) data[idx + 3] = excl + v.x + v.y + v.z;
}

__global__ __launch_bounds__(256) void scan_sums(int* __restrict__ bsum, int nb)
{
    __shared__ int s[256];
    int t = threadIdx.x;
    int v = (t < nb) ? bsum[t] : 0;
    s[t] = v;
    __syncthreads();
    for (int off = 1; off < 256; off <<= 1) {
        int x = (t >= off) ? s[t - off] : 0;
        __syncthreads();
        s[t] += x;
        __syncthreads();
    }
    if (t < nb) bsum[t] = s[t] - v;
}

__global__ __launch_bounds__(256) void scan_add(
    int* __restrict__ data, int n, const int* __restrict__ bsum)
{
    int i = blockIdx.x * 256 + threadIdx.x;
    if (i < n) data[i] += bsum[i >> 10];
}

__global__ __launch_bounds__(256) void pass1_scatter(
    const int* __restrict__ ei, int E, int Etot, int NB, int chunk,
    const int* __restrict__ S, unsigned* __restrict__ tmp)
{
    __shared__ int cur[MAXNB];
    int g = blockIdx.x;
    for (int i = threadIdx.x; i < NB; i += 256) cur[i] = S[i * GRP + g];
    __syncthreads();
    int lo = g * chunk, hi = min(Etot, lo + chunk);
    for (int e = lo + threadIdx.x; e < hi; e += 256) {
        int src, dst;
        if (e < E) { src = ei[e]; dst = ei[E + e]; }
        else       { src = dst = e - E; }
        int pos = atomicAdd(&cur[dst >> 7], 1);   // LDS atomic, private row
        tmp[pos] = ((unsigned)src << 7) | (unsigned)(dst & (BKN - 1));
    }
}

__global__ __launch_bounds__(256) void pass2_sort(
    const unsigned* __restrict__ tmp, const int* __restrict__ S,
    int NB, int Etot,
    int* __restrict__ offs, int* __restrict__ esrc, int n)
{
    __shared__ int cnt[BKN];
    __shared__ int sc[BKN];
    __shared__ int cur[BKN];
    int bk = blockIdx.x;
    int t  = threadIdx.x;
    if (t < BKN) cnt[t] = 0;
    __syncthreads();
    int lo = S[bk * GRP];
    int hi = (bk + 1 < NB) ? S[(bk + 1) * GRP] : Etot;
    for (int i = lo + t; i < hi; i += 256)
        atomicAdd(&cnt[tmp[i] & (BKN - 1)], 1);
    __syncthreads();
    int v = (t < BKN) ? cnt[t] : 0;
    if (t < BKN) sc[t] = v;
    __syncthreads();
    for (int off = 1; off < BKN; off <<= 1) {
        int x = (t < BKN && t >= off) ? sc[t - off] : 0;
        __syncthreads();
        if (t < BKN) sc[t] += x;
        __syncthreads();
    }
    if (t < BKN) {
        int node = bk * BKN + t;
        if (node < n) offs[node] = lo + sc[t];   // inclusive scan -> end(v)
        cur[t] = lo + sc[t] - v;                 // exclusive -> begin cursor
    }
    __syncthreads();
    for (int i = lo + t; i < hi; i += 256) {
        unsigned w = tmp[i];
        int p = atomicAdd(&cur[w & (BKN - 1)], 1);
        esrc[p] = (int)(w >> 7);
    }
}

// ---------------------------------------------------------------------------
// Layer-1 aggregation: one wave per dst node; HALF-WAVE per edge.
// Lane (half,li): li in [0,32) loads half4 -> features 4li..4li+3, all in
// head li>>3. Two edges per wave-level vmem instruction; unroll x2 per half.
// Cross-half combine via shfl_xor(32). Fuses normalize + bias + ELU.
// ---------------------------------------------------------------------------
__global__ __launch_bounds__(256) void agg1(
    const int* __restrict__ offs, const int* __restrict__ esrc,
    const half4* __restrict__ H4, const float* __restrict__ As,
    const float* __restrict__ Ad, const float* __restrict__ bias,
    float* __restrict__ X2, int n)
{
    int v    = (blockIdx.x * 256 + threadIdx.x) >> 6;
    int lane = threadIdx.x & 63;
    if (v >= n) return;
    int half = lane >> 5;
    int li   = lane & 31;
    int head = li >> 3;
    int end = offs[v];
    int beg = v ? offs[v - 1] : 0;
    float adv = Ad[(size_t)v * 4 + head];
    float a0 = 0.f, a1 = 0.f, a2 = 0.f, a3 = 0.f, den = 0.f;
    int j = beg + half;
    for (; j + 3 < end; j += 4) {          // edges j and j+2 for this half
        int s0 = esrc[j], s1 = esrc[j + 2];
        float e0 = As[(size_t)s0 * 4 + head] + adv;
        float e1 = As[(size_t)s1 * 4 + head] + adv;
        half4 q0 = H4[(unsigned)s0 * 32 + li];
        half4 q1 = H4[(unsigned)s1 * 32 + li];
        e0 = e0 > 0.f ? e0 : NEG_SLOPE * e0;  float w0 = __expf(e0);
        e1 = e1 > 0.f ? e1 : NEG_SLOPE * e1;  float w1 = __expf(e1);
        float4 f0 = h4_to_f4(q0);
        float4 f1 = h4_to_f4(q1);
        a0 += w0 * f0.x + w1 * f1.x;
        a1 += w0 * f0.y + w1 * f1.y;
        a2 += w0 * f0.z + w1 * f1.z;
        a3 += w0 * f0.w + w1 * f1.w;
        den += w0 + w1;
    }
    for (; j < end; j += 2) {
        int s = esrc[j];
        float e = As[(size_t)s * 4 + head] + adv;
        e = e > 0.f ? e : NEG_SLOPE * e;
        float w = __expf(e);
        float4 f = h4_to_f4(H4[(unsigned)s * 32 + li]);
        a0 += w * f.x; a1 += w * f.y; a2 += w * f.z; a3 += w * f.w;
        den += w;
    }
    a0 += __shfl_xor(a0, 32);
    a1 += __shfl_xor(a1, 32);
    a2 += __shfl_xor(a2, 32);
    a3 += __shfl_xor(a3, 32);
    den += __shfl_xor(den, 32);
    if (half == 0) {
        float inv = 1.f / (den + 1e-16f);
        float4 b = ((const float4*)bias)[li];
        float o0 = a0 * inv + b.x, o1 = a1 * inv + b.y;
        float o2 = a2 * inv + b.z, o3 = a3 * inv + b.w;
        o0 = o0 > 0.f ? o0 : __expf(o0) - 1.f;
        o1 = o1 > 0.f ? o1 : __expf(o1) - 1.f;
        o2 = o2 > 0.f ? o2 : __expf(o2) - 1.f;
        o3 = o3 > 0.f ? o3 : __expf(o3) - 1.f;
        ((float4*)(X2 + (size_t)v * 128))[li] = make_float4(o0, o1, o2, o3);
    }
}

// ---------------------------------------------------------------------------
// Layer-2 aggregation: one wave per dst node; QUARTER-WAVE per edge.
// Lane (q,li): li in [0,16) loads half4 -> features 4li..4li+3 (1 head).
// Four edges per wave-level vmem instruction; unroll x2 per quarter.
// Combine via shfl_xor(16) + shfl_xor(32). Writes d_out (fp32).
// ---------------------------------------------------------------------------
__global__ __launch_bounds__(256) void agg2(
    const int* __restrict__ offs, const int* __restrict__ esrc,
    const half4* __restrict__ H4, const float* __restrict__ As,
    const float* __restrict__ Ad, const float* __restrict__ bias,
    float* __restrict__ out, int n)
{
    int v    = (blockIdx.x * 256 + threadIdx.x) >> 6;
    int lane = threadIdx.x & 63;
    if (v >= n) return;
    int q  = lane >> 4;
    int li = lane & 15;
    int end = offs[v];
    int beg = v ? offs[v - 1] : 0;
    float adv = Ad[v];
    float a0 = 0.f, a1 = 0.f, a2 = 0.f, a3 = 0.f, den = 0.f;
    int j = beg + q;
    for (; j + 7 < end; j += 8) {          // edges j and j+4 for this quarter
        int s0 = esrc[j], s1 = esrc[j + 4];
        float e0 = As[s0] + adv;
        float e1 = As[s1] + adv;
        half4 q0 = H4[(unsigned)s0 * 16 + li];
        half4 q1 = H4[(unsigned)s1 * 16 + li];
        e0 = e0 > 0.f ? e0 : NEG_SLOPE * e0;  float w0 = __expf(e0);
        e1 = e1 > 0.f ? e1 : NEG_SLOPE * e1;  float w1 = __expf(e1);
        float4 f0 = h4_to_f4(q0);
        float4 f1 = h4_to_f4(q1);
        a0 += w0 * f0.x + w1 * f1.x;
        a1 += w0 * f0.y + w1 * f1.y;
        a2 += w0 * f0.z + w1 * f1.z;
        a3 += w0 * f0.w + w1 * f1.w;
        den += w0 + w1;
    }
    for (; j < end; j += 4) {
        int s = esrc[j];
        float e = As[s] + adv;
        e = e > 0.f ? e : NEG_SLOPE * e;
        float w = __expf(e);
        float4 f = h4_to_f4(H4[(unsigned)s * 16 + li]);
        a0 += w * f.x; a1 += w * f.y; a2 += w * f.z; a3 += w * f.w;
        den += w;
    }
    #pragma unroll
    for (int off = 16; off <= 32; off <<= 1) {
        a0 += __shfl_xor(a0, off);
        a1 += __shfl_xor(a1, off);
        a2 += __shfl_xor(a2, off);
        a3 += __shfl_xor(a3, off);
        den += __shfl_xor(den, off);
    }
    if (lane < 16) {
        float inv = 1.f / (den + 1e-16f);
        float4 b = ((const float4*)bias)[li];
        ((float4*)(out + (size_t)v * 64))[li] =
            make_float4(a0 * inv + b.x, a1 * inv + b.y,
                        a2 * inv + b.z, a3 * inv + b.w);
    }
}

extern "C" void kernel_launch(void* const* d_in, const int* in_sizes, int n_in,
                              void* d_out, int out_size, void* d_ws, size_t ws_size,
                              hipStream_t stream)
{
    (void)n_in; (void)out_size; (void)ws_size;
    const float* x   = (const float*)d_in[0];
    const int*   ei  = (const int*)  d_in[1];
    const float* W1  = (const float*)d_in[2];
    const float* as1 = (const float*)d_in[3];
    const float* ad1 = (const float*)d_in[4];
    const float* b1  = (const float*)d_in[5];
    const float* W2  = (const float*)d_in[6];
    const float* as2 = (const float*)d_in[7];
    const float* ad2 = (const float*)d_in[8];
    const float* b2  = (const float*)d_in[9];
    float* out = (float*)d_out;

    const int n    = in_sizes[0] / 128;   // 100000
    const int E    = in_sizes[1] / 2;     // 1600000
    const int Etot = E + n;               // + self loops
    const int NB   = (n + BKN - 1) / BKN; // buckets (782)
    const int chunk = (Etot + GRP - 1) / GRP;

    // Workspace layout (bytes). Layer-2 buffers overlay consumed layer-1 ones.
    char* p = (char*)d_ws;
    half_t* Hh = (half_t*)p;  p += (size_t)n * 128 * sizeof(half_t);  // 25.6MB
    float* X2  = (float*)p;   p += (size_t)n * 128 * sizeof(float);   // 51.2MB
    float* As1 = (float*)p;   p += (size_t)n * 4 * sizeof(float);     // (L2: As2=n)
    float* Ad1 = (float*)p;   p += (size_t)n * 4 * sizeof(float);     // (L2: Ad2=n)
    int* offs  = (int*)p;     p += (size_t)n * sizeof(int);
    int* esrc  = (int*)p;     p += (size_t)Etot * sizeof(int);
    unsigned* tmp = (unsigned*)p; p += (size_t)Etot * sizeof(unsigned);
    int* cnt   = (int*)p;     p += (size_t)NB * GRP * sizeof(int);    // 0.8MB
    int* bsum  = (int*)p;     p += 1024;
    half_t* Wt1 = (half_t*)p; p += 128 * 128 * sizeof(half_t);        // 32KB
    half_t* Wt2 = (half_t*)p; p += 64 * 128 * sizeof(half_t);         // 16KB

    const int scan_n  = NB * GRP;
    const int scan_nb = (scan_n + 1023) / 1024;   // <=256

    // ---- weight convert (both layers, one launch) ----
    w_convert2<<<(128 * 192 + 255) / 256, 256, 0, stream>>>(W1, Wt1, W2, Wt2);

    // ---- CSR build (contention-free bucketed counting sort) ----
    ghist<<<GRP, 256, 0, stream>>>(ei, E, Etot, NB, chunk, cnt);
    scan_blocks<<<scan_nb, 256, 0, stream>>>(cnt, scan_n, bsum);
    scan_sums<<<1, 256, 0, stream>>>(bsum, scan_nb);
    scan_add<<<(scan_n + 255) / 256, 256, 0, stream>>>(cnt, scan_n, bsum);
    pass1_scatter<<<GRP, 256, 0, stream>>>(ei, E, Etot, NB, chunk, cnt, tmp);
    pass2_sort<<<NB, 256, 0, stream>>>(tmp, cnt, NB, Etot, offs, esrc, n);

    const int gtiles = (n + 63) / 64;

    // ---- Layer 1 ----
    gemm_mfma<128, 4><<<gtiles, 256, 0, stream>>>(x, Wt1, as1, ad1, Hh, As1, Ad1, n);
    agg1<<<(n * 64 + 255) / 256, 256, 0, stream>>>(offs, esrc, (const half4*)Hh, As1, Ad1, b1, X2, n);

    // ---- Layer 2 ----
    gemm_mfma<64, 1><<<gtiles, 256, 0, stream>>>(X2, Wt2, as2, ad2, Hh, As1, Ad1, n);
    agg2<<<(n * 64 + 255) / 256, 256, 0, stream>>>(offs, esrc, (const half4*)Hh, As1, Ad1, b2, out, n);
}